// Round 22
// baseline (78.899 us; speedup 1.0000x reference)
//
#include <hip/hip_runtime.h>
#include <hip/hip_bf16.h>
#include <stdint.h>

#define BATCH 8
#define NPOS 4096   // H*W = 64*64
#define LOG2E 1.4426950408889634f

typedef __attribute__((ext_vector_type(4)))  float f32x4;
typedef __attribute__((ext_vector_type(16))) float f32x16;
typedef __attribute__((ext_vector_type(8)))  short bf16x8;

// Native 2^x. Raw inline-asm v_exp_f32 is UNSAFE (r6: TRANS hazard invisible).
// Builtin is compiler-visible. r9 lesson: must pair with chunked
// immediate-consume + sched_barrier or the scheduler hoists all 16 exps ->
// spill cliff (r10-r21: pattern works, no spills).
#if __has_builtin(__builtin_amdgcn_exp2f)
#define EXP2(x) __builtin_amdgcn_exp2f(x)
#else
#define EXP2(x) exp2f(x)
#endif

// sched_barrier mask: MFMA|VMEM*|DS* may cross, VALU/TRANS/SALU may not.
#define SOFTMAX_FENCE() __builtin_amdgcn_sched_barrier(0x3F8)

__device__ __forceinline__ unsigned short bf_rne(float f) {
    unsigned u = __float_as_uint(f);
    u += 0x7fffu + ((u >> 16) & 1u);
    return (unsigned short)(u >> 16);
}
__device__ __forceinline__ unsigned cvt_pk_bf16(float lo, float hi) {
    unsigned r;
    asm("v_cvt_pk_bf16_f32 %0, %1, %2" : "=v"(r) : "v"(lo), "v"(hi));
    return r;
}
__device__ __forceinline__ void permswap32(unsigned &a, unsigned &b) {
    asm volatile("v_permlane32_swap_b32 %0, %1" : "+v"(a), "+v"(b));
}

// ---------------------------------------------------------------------------
// FRAGMENT-MAJOR layouts (r13/r15: K -> LDS pipe conflict-free, V -> L2/TCP
// pipe coalesced; SQ_LDS_BANK_CONFLICT = 0 measured r15-r21):
//   KF[b][st 64][it 2][kk 4][g2 2][r31 32][e 8]  bf16  (4 MB)
//     element = K[key=st*64+it*32+r31][ch=kk*16+g2*8+e]
//   VF[b][st 64][it 2][h 2][c 2][g2 2][r31 32][e 8]  bf16  (4 MB)
//     element = V[ch=h*32+r31][key=st*64+it*32+c*16+g2*8+e]
//
// REGALLOC VERDICT (r16/r19): depth-2 V pipelining does NOT fit -- backend
// pins VGPR=64 regardless of launch_bounds/waves_per_eu attrs; extra live
// regs become 150+ MB scratch (2x slowdown). DO NOT re-add the pipeline.
// CONV VERDICT (r20): f32x2 elementwise_fma pairing REGRESSED ~9 us. Scalar.
// ---------------------------------------------------------------------------

// Kernel 1: both 1x1 convs. Grid 8192 = (b, nb, pass, oe 0..7); 64 threads.
// 8 output channels per thread (r21 post-mortem: conv at 14us vs ~4us VALU
// floor was latency-bound at 4 waves/SIMD; 8-way split -> 8 waves/SIMD).
// Scalar fmaf chain; W/bias reads wave-uniform -> s_load.
__global__ __launch_bounds__(64)
void conv_prep(const float* __restrict__ xlow, const float* __restrict__ xhigh,
               const float* __restrict__ Wl, const float* __restrict__ bl,
               const float* __restrict__ Wh, const float* __restrict__ bh,
               unsigned short* __restrict__ KF, unsigned short* __restrict__ QThi,
               unsigned short* __restrict__ VF, float* __restrict__ R32)
{
    const int id   = blockIdx.x;
    const int b    = id & 7;
    const int rest = id >> 3;
    const int nb   = rest & 63;
    const int pass = (rest >> 6) & 1;  // 0 = low (K), 1 = high (Q/V/R)
    const int oe   = rest >> 7;        // 0..7 channel eighth
    const int t    = threadIdx.x;
    const int n    = nb * 64 + t;
    const int o0   = oe * 8;

    const float* __restrict__ x    = pass ? xhigh : xlow;
    const float* __restrict__ W    = pass ? Wh : Wl;
    const float* __restrict__ bias = pass ? bh : bl;

    float xr[64];
#pragma unroll
    for (int i = 0; i < 64; ++i)
        xr[i] = x[((size_t)(b * 64 + i)) * NPOS + n];

    // VF scatter base: st=nb, it=(t>>5)&1, c=(t>>4)&1, g2=(t>>3)&1, e=t&7;
    // ch = o0+oo -> h = oe>>2, r31 = (oe&3)*8 + oo  (r31 stride = 16B)
    char* vbase = (char*)VF + ((size_t)b << 19) + nb * 8192 + ((t >> 5) & 1) * 4096
                + (oe >> 2) * 2048 + ((t >> 4) & 1) * 1024 + ((t >> 3) & 1) * 512
                + (oe & 3) * 128 + (t & 7) * 2;

    unsigned hpack[4];
#pragma unroll
    for (int oo = 0; oo < 8; ++oo) {
        const int o = o0 + oo;
        float acc = bias[o];
#pragma unroll
        for (int i = 0; i < 64; ++i)
            acc = fmaf(W[o * 64 + i], xr[i], acc);   // W reads wave-uniform -> s_load

        if (pass) {
            *(unsigned short*)(vbase + oo * 16) = bf_rne(acc);
            R32[((size_t)(b * 64 + o)) * NPOS + n] = acc;
        }
        unsigned short h = bf_rne(pass ? acc * LOG2E : acc);
        if (oo & 1) hpack[oo >> 1] |= ((unsigned)h) << 16;
        else        hpack[oo >> 1]  = h;
    }

    uint4 v0; v0.x = hpack[0]; v0.y = hpack[1]; v0.z = hpack[2]; v0.w = hpack[3];
    if (pass) {
        // Q row-major: 8 channels = one aligned 16B store
        *(uint4*)(QThi + ((size_t)(b * NPOS + n)) * 64 + o0) = v0;
    } else {
        // KF frag-major: key=n -> st=nb, it=(t>>5)&1, r31=t&31; kk=oe>>1, g2=oe&1
        char* kbase = (char*)KF + ((size_t)b << 19) + nb * 8192 + ((t >> 5) & 1) * 4096
                    + (oe >> 1) * 1024 + (oe & 1) * 512 + (t & 31) * 16;
        *(uint4*)kbase = v0;
    }
}

// ---------------------------------------------------------------------------
// K staging: one 8KB supertile of KF -> linear LDS; each wave copies a
// contiguous 1KB chunk. global_load_lds source is PER-LANE (+lane*16);
// LDS dest = uniform base + lane*16 (r14 bug lesson).
// ---------------------------------------------------------------------------
__device__ __forceinline__ void stage_k(const unsigned short* __restrict__ KF,
                                        int b, int st, char* dst, int w, int lane)
{
    const char* src = (const char*)KF + ((size_t)b << 19) + (size_t)st * 8192
                    + w * 1024 + lane * 16;
    __builtin_amdgcn_global_load_lds(
        (const __attribute__((address_space(1))) unsigned int*)(const void*)src,
        (__attribute__((address_space(3))) unsigned int*)(void*)(dst + w * 1024),
        16, 0, 0);
}

// ---------------------------------------------------------------------------
// Kernel 2: flash attention partials -- r15 per-half-step structure, now
// with a 4-DEEP K LDS RING (4 x 8KB) and ONE BARRIER PER 2 SUPERTILES
// (r21 post-mortem: no pipe >34% busy -> dependency/lockstep-bound; the 16
// per-supertile barriers re-locksteped all 16 waves; halving barrier events
// lets waves drift a supertile apart so phases overlap across waves).
// Ring safety: buffers staged in iter k were last read in iter k-1
// (separated by the end-of-iter barrier); reads of newly staged buffers are
// guarded by the same barrier's implicit vmcnt(0) drain. nst always even.
// Grid = 8 b x 16 qb x nsplit(4) = 512 blocks = 2 blocks/CU = 16 waves/CU.
// FIXED-SCALE softmax (validated r7-r21): p = exp2(sA), plain-sum combine.
// ---------------------------------------------------------------------------
__global__ __launch_bounds__(512, 4)
void attn_fused(const unsigned short* __restrict__ KF,
                const unsigned short* __restrict__ QThi,
                const unsigned short* __restrict__ VF,
                unsigned short* __restrict__ Pacc, float* __restrict__ Lp,
                int nsplit)
{
    const int id   = blockIdx.x;
    const int b    = id & 7;            // one batch per XCD
    const int qb   = (id >> 3) & 15;    // q-block (256 rows)
    const int s    = id >> 7;           // KV split index
    const int tid  = threadIdx.x;
    const int w    = tid >> 6;          // 0..7
    const int lane = tid & 63;
    const int r31  = lane & 31;
    const int g2   = lane >> 5;

    const int st0 = (64 * s) / nsplit;
    const int nst = (64 * (s + 1)) / nsplit - st0;   // 16/32/64: always even

    __shared__ __align__(1024) char smem[32768];   // 4 x 8KB K ring buffers

    // Q fragments hoisted (B-operand: col=lane&31=q, k=(lane>>5)*8+e)
    const int qrow = qb * 256 + w * 32 + r31;
    bf16x8 qhi[4];
#pragma unroll
    for (int kk = 0; kk < 4; ++kk)
        qhi[kk] = *(const bf16x8*)(QThi + ((size_t)b * NPOS + qrow) * 64 + kk * 16 + g2 * 8);

    f32x16 accO0, accO1;
#pragma unroll
    for (int r = 0; r < 16; ++r) { accO0[r] = 0.f; accO1[r] = 0.f; }
    float l_run = 0.f;

    stage_k(KF, b, st0,     smem,        w, lane);
    stage_k(KF, b, st0 + 1, smem + 8192, w, lane);
    __syncthreads();

    for (int stp = 0; stp < nst; stp += 2) {
        if (stp + 2 < nst) {
            stage_k(KF, b, st0 + stp + 2, smem + ((stp + 2) & 3) * 8192, w, lane);
            stage_k(KF, b, st0 + stp + 3, smem + ((stp + 3) & 3) * 8192, w, lane);
        }

#pragma unroll
        for (int sub = 0; sub < 2; ++sub) {
            const int st  = stp + sub;
            char* buf = smem + (st & 3) * 8192;

#pragma unroll
            for (int itx = 0; itx < 2; ++itx) {
                const int it = itx ^ (w & 1);   // wave-staggered phase order

                // ---- QK^T: K frags from LDS (lane-contiguous, conflict-free) ----
                f32x16 sA;
#pragma unroll
                for (int r = 0; r < 16; ++r) sA[r] = 0.f;
                const char* Kb = buf + it * 4096;
                __builtin_amdgcn_s_setprio(1);
#pragma unroll
                for (int kk = 0; kk < 4; ++kk) {
                    bf16x8 kh = *(const bf16x8*)(Kb + kk * 1024 + lane * 16);
                    sA = __builtin_amdgcn_mfma_f32_32x32x16_bf16(kh, qhi[kk], sA, 0, 0, 0);
                }
                __builtin_amdgcn_s_setprio(0);

                // ---- V frags from GLOBAL (latency hides under softmax;
                // coalesced 1KB/wave-load, L2-resident) ----
                const char* vbase = (const char*)VF + ((size_t)b << 19)
                                  + (size_t)(st0 + st) * 8192 + it * 4096 + lane * 16;
                bf16x8 vf00 = *(const bf16x8*)(vbase);          // h=0 c=0
                bf16x8 vf01 = *(const bf16x8*)(vbase + 1024);   // h=0 c=1
                bf16x8 vf10 = *(const bf16x8*)(vbase + 2048);   // h=1 c=0
                bf16x8 vf11 = *(const bf16x8*)(vbase + 3072);   // h=1 c=1

                // ---- fixed-scale softmax, chunked (r9 spill fix) ----
                unsigned wpk[8];
                float lr0 = 0.f, lr1 = 0.f;
#pragma unroll
                for (int h = 0; h < 8; ++h) {
                    float pa = EXP2(sA[2 * h]);
                    float pb = EXP2(sA[2 * h + 1]);
                    wpk[h] = cvt_pk_bf16(pa, pb);
                    lr0 += pa;
                    lr1 += pb;
                    if (h & 1) SOFTMAX_FENCE();
                }
                l_run += lr0 + lr1;

                // ---- P half-exchange (permlane32_swap) -> B-frags ----
                unsigned a0 = wpk[0], b0 = wpk[2]; permswap32(a0, b0);
                unsigned a1 = wpk[1], b1 = wpk[3]; permswap32(a1, b1);
                unsigned a2 = wpk[4], b2 = wpk[6]; permswap32(a2, b2);
                unsigned a3 = wpk[5], b3 = wpk[7]; permswap32(a3, b3);
                union { unsigned u[4]; bf16x8 v; } fa0, fa1;
                fa0.u[0] = a0; fa0.u[1] = a1; fa0.u[2] = b0; fa0.u[3] = b1;
                fa1.u[0] = a2; fa1.u[1] = a3; fa1.u[2] = b2; fa1.u[3] = b3;

                // ---- PV: O^T += V^T · P ----
                __builtin_amdgcn_s_setprio(1);
                accO0 = __builtin_amdgcn_mfma_f32_32x32x16_bf16(vf00, fa0.v, accO0, 0, 0, 0);
                accO0 = __builtin_amdgcn_mfma_f32_32x32x16_bf16(vf01, fa1.v, accO0, 0, 0, 0);
                accO1 = __builtin_amdgcn_mfma_f32_32x32x16_bf16(vf10, fa0.v, accO1, 0, 0, 0);
                accO1 = __builtin_amdgcn_mfma_f32_32x32x16_bf16(vf11, fa1.v, accO1, 0, 0, 0);
                __builtin_amdgcn_s_setprio(0);
            }
        }
        __syncthreads();   // ring safety + staging vmcnt drain (1 per 2 tiles)
    }

    // ---- epilogue: bf16 partials, O^T layout [64 d][256 q]; l reduced once ----
    const float l_tot = l_run + __shfl_xor(l_run, 32, 64);
#pragma unroll
    for (int r = 0; r < 16; ++r) {
        const int d0 = (r & 3) + 8 * (r >> 2) + 4 * g2;
        Pacc[(size_t)id * 16384 + (size_t)d0 * 256 + w * 32 + r31]        = bf_rne(accO0[r]);
        Pacc[(size_t)id * 16384 + (size_t)(d0 + 32) * 256 + w * 32 + r31] = bf_rne(accO1[r]);
    }
    if (g2 == 0)
        Lp[(size_t)id * 256 + w * 32 + r31] = l_tot;
}

// ---------------------------------------------------------------------------
// Kernel 3: combine = plain sum of bf16 partials / sum of l + residual.
// LINE-ONCE reads (r13 fix): s outer, 32B contiguous per thread/split.
// nsplit=4 -> Pacc 16.8 MB -> ~25 MB read.
// ---------------------------------------------------------------------------
__global__ __launch_bounds__(256)
void attn_combine(const unsigned short* __restrict__ Pacc, const float* __restrict__ Lp,
                  const float* __restrict__ R32, float* __restrict__ out, int nsplit)
{
    const int cid     = blockIdx.x;
    const int quarter = cid & 3;
    const int b       = (cid >> 2) & 7;
    const int qb      = cid >> 5;        // 0..15
    const int t       = threadIdx.x;

    __shared__ float invL[256];

    {
        float L = 0.f;
        for (int s = 0; s < nsplit; ++s)
            L += Lp[(size_t)((s << 7) | (qb << 3) | b) * 256 + t];
        invL[t] = 1.0f / L;
    }
    __syncthreads();

    const int c_loc = t >> 4;                 // 0..15
    const int c     = quarter * 16 + c_loc;   // 0..63
    const int q0    = (t & 15) * 16;          // 0..240

    float acc[16];
#pragma unroll
    for (int i = 0; i < 16; ++i) acc[i] = 0.f;

    for (int s = 0; s < nsplit; ++s) {
        const size_t p = (size_t)((s << 7) | (qb << 3) | b);
        const bf16x8* pp = (const bf16x8*)(Pacc + p * 16384 + (size_t)c * 256 + q0);
#pragma unroll
        for (int h = 0; h < 2; ++h) {
            bf16x8 v = pp[h];
#pragma unroll
            for (int e = 0; e < 8; ++e)
                acc[h * 8 + e] += __uint_as_float(((unsigned)(unsigned short)v[e]) << 16);
        }
    }

    const size_t obase = ((size_t)(b * 64 + c)) * NPOS + qb * 256 + q0;
#pragma unroll
    for (int hv = 0; hv < 4; ++hv) {
        f32x4 rv = *(const f32x4*)(R32 + obase + hv * 4);
        f32x4 v;
#pragma unroll
        for (int e = 0; e < 4; ++e)
            v[e] = acc[hv * 4 + e] * invL[q0 + hv * 4 + e] + rv[e];
        *(f32x4*)(out + obase + hv * 4) = v;
    }
}

// ---------------------------------------------------------------------------
extern "C" void kernel_launch(void* const* d_in, const int* in_sizes, int n_in,
                              void* d_out, int out_size, void* d_ws, size_t ws_size,
                              hipStream_t stream)
{
    const float* xlow  = (const float*)d_in[0];
    const float* xhigh = (const float*)d_in[1];
    const float* Wl    = (const float*)d_in[2];
    const float* bl    = (const float*)d_in[3];
    const float* Wh    = (const float*)d_in[4];
    const float* bh    = (const float*)d_in[5];

    char* ws = (char*)d_ws;
    unsigned short* KF   = (unsigned short*)(ws);                  // 4 MB frag-major
    unsigned short* QThi = (unsigned short*)(ws + ( 4u << 20));    // 4 MB row-major
    unsigned short* VF   = (unsigned short*)(ws + ( 8u << 20));    // 4 MB frag-major
    float*          R32  = (float*)         (ws + (12u << 20));    // 8 MB -> 20 MB

    const size_t base = (size_t)20u << 20;
    // nsplit=4 -> grid 512 = exactly 2 blocks/CU (r11/r20/r21).
    int nsplit = 4;
    while (nsplit > 1) {
        size_t nblk = (size_t)128 * nsplit;
        size_t need = base + nblk * 16384 * 2 + nblk * 256 * 4;
        if (need <= ws_size) break;
        nsplit >>= 1;
    }
    const size_t nblk = (size_t)128 * nsplit;
    unsigned short* Pacc = (unsigned short*)(ws + base);
    float*          Lp   = (float*)(ws + base + nblk * 16384 * 2);

    conv_prep<<<dim3(8192), dim3(64), 0, stream>>>(
        xlow, xhigh, Wl, bl, Wh, bh, KF, QThi, VF, R32);
    attn_fused<<<dim3((unsigned)nblk), dim3(512), 0, stream>>>(
        KF, QThi, VF, Pacc, Lp, nsplit);
    attn_combine<<<dim3(512), dim3(256), 0, stream>>>(
        Pacc, Lp, R32, (float*)d_out, nsplit);
}

// Round 23
// 76.232 us; speedup vs baseline: 1.0350x; 1.0350x over previous
//
#include <hip/hip_runtime.h>
#include <hip/hip_bf16.h>
#include <stdint.h>

#define BATCH 8
#define NPOS 4096   // H*W = 64*64
#define LOG2E 1.4426950408889634f

typedef __attribute__((ext_vector_type(4)))  float f32x4;
typedef __attribute__((ext_vector_type(16))) float f32x16;
typedef __attribute__((ext_vector_type(8)))  short bf16x8;

// Native 2^x. Raw inline-asm v_exp_f32 is UNSAFE (r6: TRANS hazard invisible).
// Builtin is compiler-visible. r9 lesson: must pair with chunked
// immediate-consume + sched_barrier or the scheduler hoists all 16 exps ->
// spill cliff (r10-r22: pattern works, no spills).
#if __has_builtin(__builtin_amdgcn_exp2f)
#define EXP2(x) __builtin_amdgcn_exp2f(x)
#else
#define EXP2(x) exp2f(x)
#endif

// sched_barrier mask: MFMA|VMEM*|DS* may cross, VALU/TRANS/SALU may not.
#define SOFTMAX_FENCE() __builtin_amdgcn_sched_barrier(0x3F8)

__device__ __forceinline__ unsigned short bf_rne(float f) {
    unsigned u = __float_as_uint(f);
    u += 0x7fffu + ((u >> 16) & 1u);
    return (unsigned short)(u >> 16);
}
__device__ __forceinline__ unsigned cvt_pk_bf16(float lo, float hi) {
    unsigned r;
    asm("v_cvt_pk_bf16_f32 %0, %1, %2" : "=v"(r) : "v"(lo), "v"(hi));
    return r;
}
__device__ __forceinline__ void permswap32(unsigned &a, unsigned &b) {
    asm volatile("v_permlane32_swap_b32 %0, %1" : "+v"(a), "+v"(b));
}

// ---------------------------------------------------------------------------
// FRAGMENT-MAJOR layouts (r13/r15: K -> LDS pipe conflict-free, V -> L2/TCP
// pipe coalesced; SQ_LDS_BANK_CONFLICT = 0 measured r15-r22):
//   KF[b][st 64][it 2][kk 4][g2 2][r31 32][e 8]  bf16  (4 MB)
//     element = K[key=st*64+it*32+r31][ch=kk*16+g2*8+e]
//   VF[b][st 64][it 2][h 2][c 2][g2 2][r31 32][e 8]  bf16  (4 MB)
//     element = V[ch=h*32+r31][key=st*64+it*32+c*16+g2*8+e]
//
// FINAL CONFIG = round-21 best (76.5 us). Measured verdicts:
// - REGALLOC (r16/r19): depth-2 V pipeline spills (backend pins VGPR=64,
//   ignores launch_bounds/waves_per_eu); 150+ MB scratch, 2x slowdown.
// - Barriers (r22): 4-deep ring + barrier/2-supertiles = null (+1 us).
// - TLP (r13/r15/r12): >16 waves/CU = null. nsplit=4 optimal (combine).
// - Conv (r20/r22): f32x2 pairing regressed; 8-way split null (VALU floor
//   13.6 us: 1M FMA/CU x 2cyc, decomposition-invariant).
// ---------------------------------------------------------------------------

// Kernel 1: both 1x1 convs. Grid 4096 = (b, nb, pass, oq); 64 threads.
// Scalar fmaf chain; W/bias reads wave-uniform -> s_load (~14us VALU floor).
__global__ __launch_bounds__(64)
void conv_prep(const float* __restrict__ xlow, const float* __restrict__ xhigh,
               const float* __restrict__ Wl, const float* __restrict__ bl,
               const float* __restrict__ Wh, const float* __restrict__ bh,
               unsigned short* __restrict__ KF, unsigned short* __restrict__ QThi,
               unsigned short* __restrict__ VF, float* __restrict__ R32)
{
    const int id   = blockIdx.x;
    const int b    = id & 7;
    const int rest = id >> 3;
    const int nb   = rest & 63;
    const int pass = (rest >> 6) & 1;  // 0 = low (K), 1 = high (Q/V/R)
    const int oq   = rest >> 7;        // 0..3 channel quarter
    const int t    = threadIdx.x;
    const int n    = nb * 64 + t;
    const int o0   = oq * 16;

    const float* __restrict__ x    = pass ? xhigh : xlow;
    const float* __restrict__ W    = pass ? Wh : Wl;
    const float* __restrict__ bias = pass ? bh : bl;

    float xr[64];
#pragma unroll
    for (int i = 0; i < 64; ++i)
        xr[i] = x[((size_t)(b * 64 + i)) * NPOS + n];

    // VF scatter base: st=nb, it=(t>>5)&1, c=(t>>4)&1, g2=(t>>3)&1, e=t&7;
    // h=oq>>1, r31=(oq&1)*16+oo -> + (oq&1)*256 + oo*16
    char* vbase = (char*)VF + ((size_t)b << 19) + nb * 8192 + ((t >> 5) & 1) * 4096
                + (oq >> 1) * 2048 + ((t >> 4) & 1) * 1024 + ((t >> 3) & 1) * 512
                + (oq & 1) * 256 + (t & 7) * 2;

    unsigned hpack[8];
#pragma unroll
    for (int oo = 0; oo < 16; ++oo) {
        const int o = o0 + oo;
        float acc = bias[o];
#pragma unroll
        for (int i = 0; i < 64; ++i)
            acc = fmaf(W[o * 64 + i], xr[i], acc);   // W reads wave-uniform -> s_load

        if (pass) {
            *(unsigned short*)(vbase + oo * 16) = bf_rne(acc);
            R32[((size_t)(b * 64 + o)) * NPOS + n] = acc;
        }
        unsigned short h = bf_rne(pass ? acc * LOG2E : acc);
        if (oo & 1) hpack[oo >> 1] |= ((unsigned)h) << 16;
        else        hpack[oo >> 1]  = h;
    }

    if (pass) {
        // Q row-major (per-block prologue gather in attn -- once per wave)
        uint4* ph = (uint4*)(QThi + ((size_t)(b * NPOS + n)) * 64 + o0);
        uint4 v0; v0.x = hpack[0]; v0.y = hpack[1]; v0.z = hpack[2]; v0.w = hpack[3];
        uint4 v1; v1.x = hpack[4]; v1.y = hpack[5]; v1.z = hpack[6]; v1.w = hpack[7];
        ph[0] = v0; ph[1] = v1;
    } else {
        // KF frag-major: key=n -> st=nb, it=(t>>5)&1, r31=t&31; kk=oq, g2=oo>>3
        char* kbase = (char*)KF + ((size_t)b << 19) + nb * 8192 + ((t >> 5) & 1) * 4096
                    + oq * 1024 + (t & 31) * 16;
        uint4 v0; v0.x = hpack[0]; v0.y = hpack[1]; v0.z = hpack[2]; v0.w = hpack[3];
        uint4 v1; v1.x = hpack[4]; v1.y = hpack[5]; v1.z = hpack[6]; v1.w = hpack[7];
        *(uint4*)kbase         = v0;   // g2=0
        *(uint4*)(kbase + 512) = v1;   // g2=1
    }
}

// ---------------------------------------------------------------------------
// K staging: one 8KB supertile of KF -> linear LDS; each wave copies a
// contiguous 1KB chunk. global_load_lds source is PER-LANE (+lane*16);
// LDS dest = uniform base + lane*16 (r14 bug lesson).
// ---------------------------------------------------------------------------
__device__ __forceinline__ void stage_k(const unsigned short* __restrict__ KF,
                                        int b, int st, char* dst, int w, int lane)
{
    const char* src = (const char*)KF + ((size_t)b << 19) + (size_t)st * 8192
                    + w * 1024 + lane * 16;
    __builtin_amdgcn_global_load_lds(
        (const __attribute__((address_space(1))) unsigned int*)(const void*)src,
        (__attribute__((address_space(3))) unsigned int*)(void*)(dst + w * 1024),
        16, 0, 0);
}

// ---------------------------------------------------------------------------
// Kernel 2: flash attention partials -- r15/r21 structure (single V issue
// per half-step; 2 x 8KB double-buffer, barrier per supertile).
// 8 waves x 32 q-rows = 256 q/block.
// Grid = 8 b x 16 qb x nsplit(4) = 512 blocks = 2 blocks/CU = 16 waves/CU.
// K: LDS conflict-free; V: global frag-major coalesced (L2-resident).
// FIXED-SCALE softmax (validated r7-r22): p = exp2(sA), plain-sum combine.
// Wave-staggered it order. bf16 partials.
// ---------------------------------------------------------------------------
__global__ __launch_bounds__(512, 4)
void attn_fused(const unsigned short* __restrict__ KF,
                const unsigned short* __restrict__ QThi,
                const unsigned short* __restrict__ VF,
                unsigned short* __restrict__ Pacc, float* __restrict__ Lp,
                int nsplit)
{
    const int id   = blockIdx.x;
    const int b    = id & 7;            // one batch per XCD
    const int qb   = (id >> 3) & 15;    // q-block (256 rows)
    const int s    = id >> 7;           // KV split index
    const int tid  = threadIdx.x;
    const int w    = tid >> 6;          // 0..7
    const int lane = tid & 63;
    const int r31  = lane & 31;
    const int g2   = lane >> 5;

    const int st0 = (64 * s) / nsplit;
    const int nst = (64 * (s + 1)) / nsplit - st0;

    __shared__ __align__(1024) char smem[16384];   // 2 x 8KB K supertile buffers

    // Q fragments hoisted (B-operand: col=lane&31=q, k=(lane>>5)*8+e)
    const int qrow = qb * 256 + w * 32 + r31;
    bf16x8 qhi[4];
#pragma unroll
    for (int kk = 0; kk < 4; ++kk)
        qhi[kk] = *(const bf16x8*)(QThi + ((size_t)b * NPOS + qrow) * 64 + kk * 16 + g2 * 8);

    f32x16 accO0, accO1;
#pragma unroll
    for (int r = 0; r < 16; ++r) { accO0[r] = 0.f; accO1[r] = 0.f; }
    float l_run = 0.f;

    stage_k(KF, b, st0, smem, w, lane);
    __syncthreads();

    for (int st = 0; st < nst; ++st) {
        char* buf = smem + (st & 1) * 8192;
        if (st + 1 < nst)
            stage_k(KF, b, st0 + st + 1, smem + ((st + 1) & 1) * 8192, w, lane);

#pragma unroll
        for (int itx = 0; itx < 2; ++itx) {
            const int it = itx ^ (w & 1);   // wave-staggered phase order

            // ---- QK^T: K frags from LDS (lane-contiguous, conflict-free) ----
            f32x16 sA;
#pragma unroll
            for (int r = 0; r < 16; ++r) sA[r] = 0.f;
            const char* Kb = buf + it * 4096;
            __builtin_amdgcn_s_setprio(1);
#pragma unroll
            for (int kk = 0; kk < 4; ++kk) {
                bf16x8 kh = *(const bf16x8*)(Kb + kk * 1024 + lane * 16);
                sA = __builtin_amdgcn_mfma_f32_32x32x16_bf16(kh, qhi[kk], sA, 0, 0, 0);
            }
            __builtin_amdgcn_s_setprio(0);

            // ---- V frags from GLOBAL (latency hides under softmax;
            // coalesced 1KB/wave-load, L2-resident) ----
            const char* vbase = (const char*)VF + ((size_t)b << 19)
                              + (size_t)(st0 + st) * 8192 + it * 4096 + lane * 16;
            bf16x8 vf00 = *(const bf16x8*)(vbase);          // h=0 c=0
            bf16x8 vf01 = *(const bf16x8*)(vbase + 1024);   // h=0 c=1
            bf16x8 vf10 = *(const bf16x8*)(vbase + 2048);   // h=1 c=0
            bf16x8 vf11 = *(const bf16x8*)(vbase + 3072);   // h=1 c=1

            // ---- fixed-scale softmax, chunked (r9 spill fix) ----
            unsigned wpk[8];
            float lr0 = 0.f, lr1 = 0.f;
#pragma unroll
            for (int h = 0; h < 8; ++h) {
                float pa = EXP2(sA[2 * h]);
                float pb = EXP2(sA[2 * h + 1]);
                wpk[h] = cvt_pk_bf16(pa, pb);
                lr0 += pa;
                lr1 += pb;
                if (h & 1) SOFTMAX_FENCE();
            }
            l_run += lr0 + lr1;

            // ---- P half-exchange (permlane32_swap) -> B-frags ----
            unsigned a0 = wpk[0], b0 = wpk[2]; permswap32(a0, b0);
            unsigned a1 = wpk[1], b1 = wpk[3]; permswap32(a1, b1);
            unsigned a2 = wpk[4], b2 = wpk[6]; permswap32(a2, b2);
            unsigned a3 = wpk[5], b3 = wpk[7]; permswap32(a3, b3);
            union { unsigned u[4]; bf16x8 v; } fa0, fa1;
            fa0.u[0] = a0; fa0.u[1] = a1; fa0.u[2] = b0; fa0.u[3] = b1;
            fa1.u[0] = a2; fa1.u[1] = a3; fa1.u[2] = b2; fa1.u[3] = b3;

            // ---- PV: O^T += V^T · P ----
            __builtin_amdgcn_s_setprio(1);
            accO0 = __builtin_amdgcn_mfma_f32_32x32x16_bf16(vf00, fa0.v, accO0, 0, 0, 0);
            accO0 = __builtin_amdgcn_mfma_f32_32x32x16_bf16(vf01, fa1.v, accO0, 0, 0, 0);
            accO1 = __builtin_amdgcn_mfma_f32_32x32x16_bf16(vf10, fa0.v, accO1, 0, 0, 0);
            accO1 = __builtin_amdgcn_mfma_f32_32x32x16_bf16(vf11, fa1.v, accO1, 0, 0, 0);
            __builtin_amdgcn_s_setprio(0);
        }
        __syncthreads();   // K dbuf safety; drains staging vmcnt (1 load/wave)
    }

    // ---- epilogue: bf16 partials, O^T layout [64 d][256 q]; l reduced once ----
    const float l_tot = l_run + __shfl_xor(l_run, 32, 64);
#pragma unroll
    for (int r = 0; r < 16; ++r) {
        const int d0 = (r & 3) + 8 * (r >> 2) + 4 * g2;
        Pacc[(size_t)id * 16384 + (size_t)d0 * 256 + w * 32 + r31]        = bf_rne(accO0[r]);
        Pacc[(size_t)id * 16384 + (size_t)(d0 + 32) * 256 + w * 32 + r31] = bf_rne(accO1[r]);
    }
    if (g2 == 0)
        Lp[(size_t)id * 256 + w * 32 + r31] = l_tot;
}

// ---------------------------------------------------------------------------
// Kernel 3: combine = plain sum of bf16 partials / sum of l + residual.
// LINE-ONCE reads (r13 fix): s outer, 32B contiguous per thread/split.
// nsplit=4 -> Pacc 16.8 MB -> ~25 MB read.
// ---------------------------------------------------------------------------
__global__ __launch_bounds__(256)
void attn_combine(const unsigned short* __restrict__ Pacc, const float* __restrict__ Lp,
                  const float* __restrict__ R32, float* __restrict__ out, int nsplit)
{
    const int cid     = blockIdx.x;
    const int quarter = cid & 3;
    const int b       = (cid >> 2) & 7;
    const int qb      = cid >> 5;        // 0..15
    const int t       = threadIdx.x;

    __shared__ float invL[256];

    {
        float L = 0.f;
        for (int s = 0; s < nsplit; ++s)
            L += Lp[(size_t)((s << 7) | (qb << 3) | b) * 256 + t];
        invL[t] = 1.0f / L;
    }
    __syncthreads();

    const int c_loc = t >> 4;                 // 0..15
    const int c     = quarter * 16 + c_loc;   // 0..63
    const int q0    = (t & 15) * 16;          // 0..240

    float acc[16];
#pragma unroll
    for (int i = 0; i < 16; ++i) acc[i] = 0.f;

    for (int s = 0; s < nsplit; ++s) {
        const size_t p = (size_t)((s << 7) | (qb << 3) | b);
        const bf16x8* pp = (const bf16x8*)(Pacc + p * 16384 + (size_t)c * 256 + q0);
#pragma unroll
        for (int h = 0; h < 2; ++h) {
            bf16x8 v = pp[h];
#pragma unroll
            for (int e = 0; e < 8; ++e)
                acc[h * 8 + e] += __uint_as_float(((unsigned)(unsigned short)v[e]) << 16);
        }
    }

    const size_t obase = ((size_t)(b * 64 + c)) * NPOS + qb * 256 + q0;
#pragma unroll
    for (int hv = 0; hv < 4; ++hv) {
        f32x4 rv = *(const f32x4*)(R32 + obase + hv * 4);
        f32x4 v;
#pragma unroll
        for (int e = 0; e < 4; ++e)
            v[e] = acc[hv * 4 + e] * invL[q0 + hv * 4 + e] + rv[e];
        *(f32x4*)(out + obase + hv * 4) = v;
    }
}

// ---------------------------------------------------------------------------
extern "C" void kernel_launch(void* const* d_in, const int* in_sizes, int n_in,
                              void* d_out, int out_size, void* d_ws, size_t ws_size,
                              hipStream_t stream)
{
    const float* xlow  = (const float*)d_in[0];
    const float* xhigh = (const float*)d_in[1];
    const float* Wl    = (const float*)d_in[2];
    const float* bl    = (const float*)d_in[3];
    const float* Wh    = (const float*)d_in[4];
    const float* bh    = (const float*)d_in[5];

    char* ws = (char*)d_ws;
    unsigned short* KF   = (unsigned short*)(ws);                  // 4 MB frag-major
    unsigned short* QThi = (unsigned short*)(ws + ( 4u << 20));    // 4 MB row-major
    unsigned short* VF   = (unsigned short*)(ws + ( 8u << 20));    // 4 MB frag-major
    float*          R32  = (float*)         (ws + (12u << 20));    // 8 MB -> 20 MB

    const size_t base = (size_t)20u << 20;
    // nsplit=4 -> grid 512 = exactly 2 blocks/CU (r11/r20/r21).
    int nsplit = 4;
    while (nsplit > 1) {
        size_t nblk = (size_t)128 * nsplit;
        size_t need = base + nblk * 16384 * 2 + nblk * 256 * 4;
        if (need <= ws_size) break;
        nsplit >>= 1;
    }
    const size_t nblk = (size_t)128 * nsplit;
    unsigned short* Pacc = (unsigned short*)(ws + base);
    float*          Lp   = (float*)(ws + base + nblk * 16384 * 2);

    conv_prep<<<dim3(4096), dim3(64), 0, stream>>>(
        xlow, xhigh, Wl, bl, Wh, bh, KF, QThi, VF, R32);
    attn_fused<<<dim3((unsigned)nblk), dim3(512), 0, stream>>>(
        KF, QThi, VF, Pacc, Lp, nsplit);
    attn_combine<<<dim3(512), dim3(256), 0, stream>>>(
        Pacc, Lp, R32, (float*)d_out, nsplit);
}

// Round 24
// 76.076 us; speedup vs baseline: 1.0371x; 1.0021x over previous
//
#include <hip/hip_runtime.h>
#include <hip/hip_bf16.h>
#include <stdint.h>

#define BATCH 8
#define NPOS 4096   // H*W = 64*64
#define LOG2E 1.4426950408889634f

typedef __attribute__((ext_vector_type(4)))  float f32x4;
typedef __attribute__((ext_vector_type(16))) float f32x16;
typedef __attribute__((ext_vector_type(8)))  short bf16x8;

// Native 2^x. Raw inline-asm v_exp_f32 is UNSAFE (r6: TRANS hazard invisible).
// Builtin is compiler-visible. r9 lesson: must pair with chunked
// immediate-consume + sched_barrier or the scheduler hoists all 16 exps ->
// spill cliff (r10-r23: pattern works, no spills).
#if __has_builtin(__builtin_amdgcn_exp2f)
#define EXP2(x) __builtin_amdgcn_exp2f(x)
#else
#define EXP2(x) exp2f(x)
#endif

// sched_barrier mask: MFMA|VMEM*|DS* may cross, VALU/TRANS/SALU may not.
#define SOFTMAX_FENCE() __builtin_amdgcn_sched_barrier(0x3F8)

__device__ __forceinline__ unsigned short bf_rne(float f) {
    unsigned u = __float_as_uint(f);
    u += 0x7fffu + ((u >> 16) & 1u);
    return (unsigned short)(u >> 16);
}
__device__ __forceinline__ unsigned cvt_pk_bf16(float lo, float hi) {
    unsigned r;
    asm("v_cvt_pk_bf16_f32 %0, %1, %2" : "=v"(r) : "v"(lo), "v"(hi));
    return r;
}
__device__ __forceinline__ void permswap32(unsigned &a, unsigned &b) {
    asm volatile("v_permlane32_swap_b32 %0, %1" : "+v"(a), "+v"(b));
}

// ---------------------------------------------------------------------------
// FRAGMENT-MAJOR layouts (r13/r15: K -> LDS pipe conflict-free, V -> L2/TCP
// pipe coalesced; SQ_LDS_BANK_CONFLICT = 0 measured r15-r23):
//   KF[b][st 64][it 2][kk 4][g2 2][r31 32][e 8]  bf16  (4 MB)
//     element = K[key=st*64+it*32+r31][ch=kk*16+g2*8+e]
//   VF[b][st 64][it 2][h 2][c 2][g2 2][r31 32][e 8]  bf16  (4 MB)
//     element = V[ch=h*32+r31][key=st*64+it*32+c*16+g2*8+e]
//
// Measured verdicts (do not revisit):
// - REGALLOC (r16/r19): depth-2 V pipeline spills (backend pins VGPR=64,
//   ignores launch_bounds/waves_per_eu); 150+ MB scratch, 2x slowdown.
// - Barriers (r22): 4-deep ring + barrier/2-supertiles = null.
// - TLP (r12/r13/r15): >16 waves/CU = null. nsplit=4 optimal (combine).
// - Conv (r20): f32x2 pairing regressed. (r22): 8-way split null.
// This round: conv inner product as 4 PARALLEL FMA CHAINS (dep distance
// 8 issue-cyc > 4-cyc fma latency) + stores moved out of the FMA stream.
// VALU floor is 3.5 us (274M FMA / 256 CU / 128 per cyc); conv measured
// ~14 -> suspected serial-chain + store-interleave stalls.
// ---------------------------------------------------------------------------

// Kernel 1: both 1x1 convs. Grid 4096 = (b, nb, pass, oq); 64 threads.
__global__ __launch_bounds__(64)
void conv_prep(const float* __restrict__ xlow, const float* __restrict__ xhigh,
               const float* __restrict__ Wl, const float* __restrict__ bl,
               const float* __restrict__ Wh, const float* __restrict__ bh,
               unsigned short* __restrict__ KF, unsigned short* __restrict__ QThi,
               unsigned short* __restrict__ VF, float* __restrict__ R32)
{
    const int id   = blockIdx.x;
    const int b    = id & 7;
    const int rest = id >> 3;
    const int nb   = rest & 63;
    const int pass = (rest >> 6) & 1;  // 0 = low (K), 1 = high (Q/V/R)
    const int oq   = rest >> 7;        // 0..3 channel quarter
    const int t    = threadIdx.x;
    const int n    = nb * 64 + t;
    const int o0   = oq * 16;

    const float* __restrict__ x    = pass ? xhigh : xlow;
    const float* __restrict__ W    = pass ? Wh : Wl;
    const float* __restrict__ bias = pass ? bh : bl;

    float xr[64];
#pragma unroll
    for (int i = 0; i < 64; ++i)
        xr[i] = x[((size_t)(b * 64 + i)) * NPOS + n];

    // ---- compute: 16 channels as 4 groups of 4 PARALLEL chains ----
    float accs[16];
#pragma unroll
    for (int og = 0; og < 4; ++og) {
        const int oA = o0 + og * 4;
        float a0 = bias[oA + 0];
        float a1 = bias[oA + 1];
        float a2 = bias[oA + 2];
        float a3 = bias[oA + 3];
        const float* __restrict__ W0 = W + (oA + 0) * 64;
        const float* __restrict__ W1 = W + (oA + 1) * 64;
        const float* __restrict__ W2 = W + (oA + 2) * 64;
        const float* __restrict__ W3 = W + (oA + 3) * 64;
#pragma unroll
        for (int i = 0; i < 64; ++i) {
            const float xv = xr[i];
            a0 = fmaf(W0[i], xv, a0);   // wave-uniform -> s_load
            a1 = fmaf(W1[i], xv, a1);
            a2 = fmaf(W2[i], xv, a2);
            a3 = fmaf(W3[i], xv, a3);
        }
        accs[og * 4 + 0] = a0;
        accs[og * 4 + 1] = a1;
        accs[og * 4 + 2] = a2;
        accs[og * 4 + 3] = a3;
    }

    // ---- stores/packing, outside the FMA stream ----
    // VF scatter base: st=nb, it=(t>>5)&1, c=(t>>4)&1, g2=(t>>3)&1, e=t&7;
    // h=oq>>1, r31=(oq&1)*16+oo -> + (oq&1)*256 + oo*16
    char* vbase = (char*)VF + ((size_t)b << 19) + nb * 8192 + ((t >> 5) & 1) * 4096
                + (oq >> 1) * 2048 + ((t >> 4) & 1) * 1024 + ((t >> 3) & 1) * 512
                + (oq & 1) * 256 + (t & 7) * 2;

    unsigned hpack[8];
#pragma unroll
    for (int oo = 0; oo < 16; ++oo) {
        const float acc = accs[oo];
        if (pass) {
            *(unsigned short*)(vbase + oo * 16) = bf_rne(acc);
            R32[((size_t)(b * 64 + o0 + oo)) * NPOS + n] = acc;
        }
        unsigned short h = bf_rne(pass ? acc * LOG2E : acc);
        if (oo & 1) hpack[oo >> 1] |= ((unsigned)h) << 16;
        else        hpack[oo >> 1]  = h;
    }

    if (pass) {
        // Q row-major (per-block prologue gather in attn -- once per wave)
        uint4* ph = (uint4*)(QThi + ((size_t)(b * NPOS + n)) * 64 + o0);
        uint4 v0; v0.x = hpack[0]; v0.y = hpack[1]; v0.z = hpack[2]; v0.w = hpack[3];
        uint4 v1; v1.x = hpack[4]; v1.y = hpack[5]; v1.z = hpack[6]; v1.w = hpack[7];
        ph[0] = v0; ph[1] = v1;
    } else {
        // KF frag-major: key=n -> st=nb, it=(t>>5)&1, r31=t&31; kk=oq, g2=oo>>3
        char* kbase = (char*)KF + ((size_t)b << 19) + nb * 8192 + ((t >> 5) & 1) * 4096
                    + oq * 1024 + (t & 31) * 16;
        uint4 v0; v0.x = hpack[0]; v0.y = hpack[1]; v0.z = hpack[2]; v0.w = hpack[3];
        uint4 v1; v1.x = hpack[4]; v1.y = hpack[5]; v1.z = hpack[6]; v1.w = hpack[7];
        *(uint4*)kbase         = v0;   // g2=0
        *(uint4*)(kbase + 512) = v1;   // g2=1
    }
}

// ---------------------------------------------------------------------------
// K staging: one 8KB supertile of KF -> linear LDS; each wave copies a
// contiguous 1KB chunk. global_load_lds source is PER-LANE (+lane*16);
// LDS dest = uniform base + lane*16 (r14 bug lesson).
// ---------------------------------------------------------------------------
__device__ __forceinline__ void stage_k(const unsigned short* __restrict__ KF,
                                        int b, int st, char* dst, int w, int lane)
{
    const char* src = (const char*)KF + ((size_t)b << 19) + (size_t)st * 8192
                    + w * 1024 + lane * 16;
    __builtin_amdgcn_global_load_lds(
        (const __attribute__((address_space(1))) unsigned int*)(const void*)src,
        (__attribute__((address_space(3))) unsigned int*)(void*)(dst + w * 1024),
        16, 0, 0);
}

// ---------------------------------------------------------------------------
// Kernel 2: flash attention partials -- r15/r21 structure (single V issue
// per half-step; 2 x 8KB double-buffer, barrier per supertile).
// 8 waves x 32 q-rows = 256 q/block.
// Grid = 8 b x 16 qb x nsplit(4) = 512 blocks = 2 blocks/CU = 16 waves/CU.
// K: LDS conflict-free; V: global frag-major coalesced (L2-resident).
// FIXED-SCALE softmax (validated r7-r23): p = exp2(sA), plain-sum combine.
// Wave-staggered it order. bf16 partials.
// ---------------------------------------------------------------------------
__global__ __launch_bounds__(512, 4)
void attn_fused(const unsigned short* __restrict__ KF,
                const unsigned short* __restrict__ QThi,
                const unsigned short* __restrict__ VF,
                unsigned short* __restrict__ Pacc, float* __restrict__ Lp,
                int nsplit)
{
    const int id   = blockIdx.x;
    const int b    = id & 7;            // one batch per XCD
    const int qb   = (id >> 3) & 15;    // q-block (256 rows)
    const int s    = id >> 7;           // KV split index
    const int tid  = threadIdx.x;
    const int w    = tid >> 6;          // 0..7
    const int lane = tid & 63;
    const int r31  = lane & 31;
    const int g2   = lane >> 5;

    const int st0 = (64 * s) / nsplit;
    const int nst = (64 * (s + 1)) / nsplit - st0;

    __shared__ __align__(1024) char smem[16384];   // 2 x 8KB K supertile buffers

    // Q fragments hoisted (B-operand: col=lane&31=q, k=(lane>>5)*8+e)
    const int qrow = qb * 256 + w * 32 + r31;
    bf16x8 qhi[4];
#pragma unroll
    for (int kk = 0; kk < 4; ++kk)
        qhi[kk] = *(const bf16x8*)(QThi + ((size_t)b * NPOS + qrow) * 64 + kk * 16 + g2 * 8);

    f32x16 accO0, accO1;
#pragma unroll
    for (int r = 0; r < 16; ++r) { accO0[r] = 0.f; accO1[r] = 0.f; }
    float l_run = 0.f;

    stage_k(KF, b, st0, smem, w, lane);
    __syncthreads();

    for (int st = 0; st < nst; ++st) {
        char* buf = smem + (st & 1) * 8192;
        if (st + 1 < nst)
            stage_k(KF, b, st0 + st + 1, smem + ((st + 1) & 1) * 8192, w, lane);

#pragma unroll
        for (int itx = 0; itx < 2; ++itx) {
            const int it = itx ^ (w & 1);   // wave-staggered phase order

            // ---- QK^T: K frags from LDS (lane-contiguous, conflict-free) ----
            f32x16 sA;
#pragma unroll
            for (int r = 0; r < 16; ++r) sA[r] = 0.f;
            const char* Kb = buf + it * 4096;
            __builtin_amdgcn_s_setprio(1);
#pragma unroll
            for (int kk = 0; kk < 4; ++kk) {
                bf16x8 kh = *(const bf16x8*)(Kb + kk * 1024 + lane * 16);
                sA = __builtin_amdgcn_mfma_f32_32x32x16_bf16(kh, qhi[kk], sA, 0, 0, 0);
            }
            __builtin_amdgcn_s_setprio(0);

            // ---- V frags from GLOBAL (latency hides under softmax;
            // coalesced 1KB/wave-load, L2-resident) ----
            const char* vbase = (const char*)VF + ((size_t)b << 19)
                              + (size_t)(st0 + st) * 8192 + it * 4096 + lane * 16;
            bf16x8 vf00 = *(const bf16x8*)(vbase);          // h=0 c=0
            bf16x8 vf01 = *(const bf16x8*)(vbase + 1024);   // h=0 c=1
            bf16x8 vf10 = *(const bf16x8*)(vbase + 2048);   // h=1 c=0
            bf16x8 vf11 = *(const bf16x8*)(vbase + 3072);   // h=1 c=1

            // ---- fixed-scale softmax, chunked (r9 spill fix) ----
            unsigned wpk[8];
            float lr0 = 0.f, lr1 = 0.f;
#pragma unroll
            for (int h = 0; h < 8; ++h) {
                float pa = EXP2(sA[2 * h]);
                float pb = EXP2(sA[2 * h + 1]);
                wpk[h] = cvt_pk_bf16(pa, pb);
                lr0 += pa;
                lr1 += pb;
                if (h & 1) SOFTMAX_FENCE();
            }
            l_run += lr0 + lr1;

            // ---- P half-exchange (permlane32_swap) -> B-frags ----
            unsigned a0 = wpk[0], b0 = wpk[2]; permswap32(a0, b0);
            unsigned a1 = wpk[1], b1 = wpk[3]; permswap32(a1, b1);
            unsigned a2 = wpk[4], b2 = wpk[6]; permswap32(a2, b2);
            unsigned a3 = wpk[5], b3 = wpk[7]; permswap32(a3, b3);
            union { unsigned u[4]; bf16x8 v; } fa0, fa1;
            fa0.u[0] = a0; fa0.u[1] = a1; fa0.u[2] = b0; fa0.u[3] = b1;
            fa1.u[0] = a2; fa1.u[1] = a3; fa1.u[2] = b2; fa1.u[3] = b3;

            // ---- PV: O^T += V^T · P ----
            __builtin_amdgcn_s_setprio(1);
            accO0 = __builtin_amdgcn_mfma_f32_32x32x16_bf16(vf00, fa0.v, accO0, 0, 0, 0);
            accO0 = __builtin_amdgcn_mfma_f32_32x32x16_bf16(vf01, fa1.v, accO0, 0, 0, 0);
            accO1 = __builtin_amdgcn_mfma_f32_32x32x16_bf16(vf10, fa0.v, accO1, 0, 0, 0);
            accO1 = __builtin_amdgcn_mfma_f32_32x32x16_bf16(vf11, fa1.v, accO1, 0, 0, 0);
            __builtin_amdgcn_s_setprio(0);
        }
        __syncthreads();   // K dbuf safety; drains staging vmcnt (1 load/wave)
    }

    // ---- epilogue: bf16 partials, O^T layout [64 d][256 q]; l reduced once ----
    const float l_tot = l_run + __shfl_xor(l_run, 32, 64);
#pragma unroll
    for (int r = 0; r < 16; ++r) {
        const int d0 = (r & 3) + 8 * (r >> 2) + 4 * g2;
        Pacc[(size_t)id * 16384 + (size_t)d0 * 256 + w * 32 + r31]        = bf_rne(accO0[r]);
        Pacc[(size_t)id * 16384 + (size_t)(d0 + 32) * 256 + w * 32 + r31] = bf_rne(accO1[r]);
    }
    if (g2 == 0)
        Lp[(size_t)id * 256 + w * 32 + r31] = l_tot;
}

// ---------------------------------------------------------------------------
// Kernel 3: combine = plain sum of bf16 partials / sum of l + residual.
// LINE-ONCE reads (r13 fix): s outer, 32B contiguous per thread/split.
// nsplit=4 -> Pacc 16.8 MB -> ~25 MB read.
// ---------------------------------------------------------------------------
__global__ __launch_bounds__(256)
void attn_combine(const unsigned short* __restrict__ Pacc, const float* __restrict__ Lp,
                  const float* __restrict__ R32, float* __restrict__ out, int nsplit)
{
    const int cid     = blockIdx.x;
    const int quarter = cid & 3;
    const int b       = (cid >> 2) & 7;
    const int qb      = cid >> 5;        // 0..15
    const int t       = threadIdx.x;

    __shared__ float invL[256];

    {
        float L = 0.f;
        for (int s = 0; s < nsplit; ++s)
            L += Lp[(size_t)((s << 7) | (qb << 3) | b) * 256 + t];
        invL[t] = 1.0f / L;
    }
    __syncthreads();

    const int c_loc = t >> 4;                 // 0..15
    const int c     = quarter * 16 + c_loc;   // 0..63
    const int q0    = (t & 15) * 16;          // 0..240

    float acc[16];
#pragma unroll
    for (int i = 0; i < 16; ++i) acc[i] = 0.f;

    for (int s = 0; s < nsplit; ++s) {
        const size_t p = (size_t)((s << 7) | (qb << 3) | b);
        const bf16x8* pp = (const bf16x8*)(Pacc + p * 16384 + (size_t)c * 256 + q0);
#pragma unroll
        for (int h = 0; h < 2; ++h) {
            bf16x8 v = pp[h];
#pragma unroll
            for (int e = 0; e < 8; ++e)
                acc[h * 8 + e] += __uint_as_float(((unsigned)(unsigned short)v[e]) << 16);
        }
    }

    const size_t obase = ((size_t)(b * 64 + c)) * NPOS + qb * 256 + q0;
#pragma unroll
    for (int hv = 0; hv < 4; ++hv) {
        f32x4 rv = *(const f32x4*)(R32 + obase + hv * 4);
        f32x4 v;
#pragma unroll
        for (int e = 0; e < 4; ++e)
            v[e] = acc[hv * 4 + e] * invL[q0 + hv * 4 + e] + rv[e];
        *(f32x4*)(out + obase + hv * 4) = v;
    }
}

// ---------------------------------------------------------------------------
extern "C" void kernel_launch(void* const* d_in, const int* in_sizes, int n_in,
                              void* d_out, int out_size, void* d_ws, size_t ws_size,
                              hipStream_t stream)
{
    const float* xlow  = (const float*)d_in[0];
    const float* xhigh = (const float*)d_in[1];
    const float* Wl    = (const float*)d_in[2];
    const float* bl    = (const float*)d_in[3];
    const float* Wh    = (const float*)d_in[4];
    const float* bh    = (const float*)d_in[5];

    char* ws = (char*)d_ws;
    unsigned short* KF   = (unsigned short*)(ws);                  // 4 MB frag-major
    unsigned short* QThi = (unsigned short*)(ws + ( 4u << 20));    // 4 MB row-major
    unsigned short* VF   = (unsigned short*)(ws + ( 8u << 20));    // 4 MB frag-major
    float*          R32  = (float*)         (ws + (12u << 20));    // 8 MB -> 20 MB

    const size_t base = (size_t)20u << 20;
    // nsplit=4 -> grid 512 = exactly 2 blocks/CU (r11/r20/r21/r23).
    int nsplit = 4;
    while (nsplit > 1) {
        size_t nblk = (size_t)128 * nsplit;
        size_t need = base + nblk * 16384 * 2 + nblk * 256 * 4;
        if (need <= ws_size) break;
        nsplit >>= 1;
    }
    const size_t nblk = (size_t)128 * nsplit;
    unsigned short* Pacc = (unsigned short*)(ws + base);
    float*          Lp   = (float*)(ws + base + nblk * 16384 * 2);

    conv_prep<<<dim3(4096), dim3(64), 0, stream>>>(
        xlow, xhigh, Wl, bl, Wh, bh, KF, QThi, VF, R32);
    attn_fused<<<dim3((unsigned)nblk), dim3(512), 0, stream>>>(
        KF, QThi, VF, Pacc, Lp, nsplit);
    attn_combine<<<dim3(512), dim3(256), 0, stream>>>(
        Pacc, Lp, R32, (float*)d_out, nsplit);
}